// Round 21
// baseline (291.775 us; speedup 1.0000x reference)
//
#include <hip/hip_runtime.h>

#define S_LEN 2048
#define DM 1024
#define NH 16
#define DH 64

typedef __attribute__((ext_vector_type(8))) short short8;
typedef __attribute__((ext_vector_type(4))) float f32x4;
typedef __attribute__((ext_vector_type(16))) float f32x16;
typedef unsigned short u16;
typedef unsigned int u32;

__device__ __forceinline__ u16 f2b(float f){
  union { float f; u32 u; } v; v.f = f;
  return (u16)((v.u + 0x7fffu + ((v.u >> 16) & 1u)) >> 16);
}
__device__ __forceinline__ float b2f(u16 h){
  union { u32 u; float f; } v; v.u = ((u32)h) << 16; return v.f;
}
// packed f32x2 -> bf16x2 (RTNE), single HW instruction
__device__ __forceinline__ u32 cvtpk(float lo, float hi){
  u32 r;
  asm("v_cvt_pk_bf16_f32 %0, %1, %2" : "=v"(r) : "v"(lo), "v"(hi));
  return r;
}

__device__ __forceinline__ f32x4 mfma16(short8 a, short8 b, f32x4 c){
  return __builtin_amdgcn_mfma_f32_16x16x32_bf16(a, b, c, 0, 0, 0);
}
__device__ __forceinline__ f32x16 mfma32(short8 a, short8 b, f32x16 c){
  return __builtin_amdgcn_mfma_f32_32x32x16_bf16(a, b, c, 0, 0, 0);
}

#define SC2 0.18033688f   /* 0.125 * log2(e) */

// raw v_exp_f32 (2^x). exp2f() without fast-math goes through OCML with
// denormal fixup (~6 extra VALU/exp = +20us measured in round 14).
#if defined(__has_builtin)
#  if __has_builtin(__builtin_amdgcn_exp2f)
#    define EXP2(x) __builtin_amdgcn_exp2f(x)
#  else
#    define EXP2(x) __expf((x) * 0.6931472f)
#  endif
#else
#  define EXP2(x) __expf((x) * 0.6931472f)
#endif

// Stage an R x 64-bf16 tile (128B rows) into LDS via global_load_lds (16B),
// XOR-swizzled: LDS stays linear, the SOURCE column-chunk is pre-swizzled
// (chunk ^= row&7), and reads apply the same XOR (both-sides rule).
// NT = threads in block.
template<int R, int NT>
__device__ __forceinline__ void stage_tile(const u16* src, int ld, u16* lds){
  const int t = threadIdx.x;
  #pragma unroll
  for (int it = 0; it < R*8/NT; ++it){
    int idx = it*NT + t;
    int row = idx >> 3;                       // 8 x 16B chunks per row
    int ch  = (idx & 7) ^ (row & 7);
    const u16* g = src + row*ld + ch*8;
    u16* l = lds + (it*NT + (t & ~63))*8;     // wave-uniform LDS base
    __builtin_amdgcn_global_load_lds((const __attribute__((address_space(1))) void*)g,
                                     (__attribute__((address_space(3))) void*)l, 16, 0, 0);
  }
}

// Reg-stage an R x 64-bf16 tile FROM AN F32 SOURCE (fused cast): coalesced
// f32x4 loads -> cvt_pk -> ds_write_b128 at the same linear-swizzled offsets
// the gload_lds path produces, so frag_ld is unchanged.
template<int R, int NT>
__device__ __forceinline__ void stage_tile_f32(const float* src, int ld, u16* lds){
  const int t = threadIdx.x;
  #pragma unroll
  for (int it = 0; it < R*8/NT; ++it){
    int idx = it*NT + t;
    int row = idx >> 3;
    int ch  = (idx & 7) ^ (row & 7);
    const float* g = src + (long)row*ld + ch*8;
    f32x4 a = *(const f32x4*)g;
    f32x4 b = *(const f32x4*)(g + 4);
    union { u32 u[4]; short8 s; } o;
    o.u[0] = cvtpk(a[0], a[1]); o.u[1] = cvtpk(a[2], a[3]);
    o.u[2] = cvtpk(b[0], b[1]); o.u[3] = cvtpk(b[2], b[3]);
    *(short8*)(lds + (long)idx*8) = o.s;
  }
}

// read one MFMA fragment (8 contiguous bf16 of row `row`, chunk `ch`)
__device__ __forceinline__ short8 frag_ld(const u16* tile, int row, int ch){
  int off = (row*128 + ch*16) ^ ((row & 7) << 4);
  return *(const short8*)((const char*)tile + off);
}

// ------ fused preprocessing: transpose+cast weights, maskb -----------------
__global__ __launch_bounds__(256) void k_pre(
    const float* __restrict__ wq, const float* __restrict__ wk,
    const float* __restrict__ wv, const float* __restrict__ wo,
    u16* __restrict__ oq, u16* __restrict__ ok, u16* __restrict__ ov, u16* __restrict__ oo,
    const float* __restrict__ mask, float* __restrict__ maskb)
{
  __shared__ float tl[64][65];
  const int bid = blockIdx.x, t = threadIdx.x;
  if (bid < 1024){
    int z = bid >> 8, rem = bid & 255;
    const float* W = (z==0)?wq:(z==1)?wk:(z==2)?wv:wo;
    u16* O = (z==0)?oq:(z==1)?ok:(z==2)?ov:oo;
    int k0 = (rem >> 4)*64, n0 = (rem & 15)*64;
    #pragma unroll
    for (int i = 0; i < 16; ++i){
      int idx2 = i*256 + t;
      int row = idx2 >> 6, col = idx2 & 63;
      tl[row][col] = W[(long)(k0+row)*DM + n0 + col];
    }
    __syncthreads();
    #pragma unroll
    for (int i = 0; i < 16; ++i){
      int idx2 = i*256 + t;
      int n = idx2 >> 6, kk = idx2 & 63;
      O[(long)(n0+n)*DM + k0 + kk] = f2b(tl[kk][n]);
    }
  } else {
    int i = (bid - 1024)*256 + t;            // 4096 elements
    maskb[i] = -1.44269504e9f * mask[i];
  }
}

// -------- fused QKV GEMM body: one side staged from f32 (cast fused) -------
__device__ __forceinline__ void gemm_body_fused(
    const void* __restrict__ Asrc, const void* __restrict__ Bsrc, int af32,
    const float* __restrict__ bias, u16* __restrict__ dst16,
    int layout, int m0, int n0, u16* At, u16* Bt)
{
  const int t = threadIdx.x, lane = t & 63, w = t >> 6;
  const int wr = (w >> 1) * 64, wc = (w & 1) * 64;
  const int li = lane & 15, lg = lane >> 4;
  const f32x4 zero = {0.f, 0.f, 0.f, 0.f};
  f32x4 acc[4][4];
  #pragma unroll
  for (int m = 0; m < 4; ++m)
    #pragma unroll
    for (int n = 0; n < 4; ++n) acc[m][n] = zero;

  for (int kt = 0; kt < DM/64; ++kt){
    if (af32){
      stage_tile_f32<128,256>((const float*)Asrc + (long)m0*DM + kt*64, DM, At);
      stage_tile<128,256>((const u16*)Bsrc + (long)n0*DM + kt*64, DM, Bt);
    } else {
      stage_tile<128,256>((const u16*)Asrc + (long)m0*DM + kt*64, DM, At);
      stage_tile_f32<128,256>((const float*)Bsrc + (long)n0*DM + kt*64, DM, Bt);
    }
    __syncthreads();
    #pragma unroll
    for (int ks = 0; ks < 2; ++ks){
      int ch = ks*4 + lg;
      short8 a[4], b[4];
      #pragma unroll
      for (int m = 0; m < 4; ++m) a[m] = frag_ld(At, wr + m*16 + li, ch);
      #pragma unroll
      for (int n = 0; n < 4; ++n) b[n] = frag_ld(Bt, wc + n*16 + li, ch);
      #pragma unroll
      for (int m = 0; m < 4; ++m)
        #pragma unroll
        for (int n = 0; n < 4; ++n) acc[m][n] = mfma16(a[m], b[n], acc[m][n]);
    }
    __syncthreads();
  }

  if (layout == 1){
    f32x4 bm[4];
    #pragma unroll
    for (int m = 0; m < 4; ++m) bm[m] = *(const f32x4*)(bias + m0 + wr + m*16 + lg*4);
    #pragma unroll
    for (int m = 0; m < 4; ++m)
      #pragma unroll
      for (int n = 0; n < 4; ++n)
        #pragma unroll
        for (int r = 0; r < 4; ++r){
          int gm = m0 + wr + m*16 + lg*4 + r;    // dm index -> (h,d)
          int gc = n0 + wc + n*16 + li;          // b*s index
          int hh = gm >> 6, dd = gm & 63, bb = gc >> 11, ss = gc & (S_LEN-1);
          dst16[(((long)(bb*NH + hh))*DH + dd)*S_LEN + ss] = f2b(acc[m][n][r] + bm[m][r]);
        }
  } else {
    float bv4[4];
    #pragma unroll
    for (int n = 0; n < 4; ++n) bv4[n] = bias[n0 + wc + n*16 + li];
    #pragma unroll
    for (int m = 0; m < 4; ++m)
      #pragma unroll
      for (int n = 0; n < 4; ++n)
        #pragma unroll
        for (int r = 0; r < 4; ++r){
          int gm = m0 + wr + m*16 + lg*4 + r;
          int gc = n0 + wc + n*16 + li;
          float val = acc[m][n][r] + bv4[n];
          int bb = gm >> 11, ss = gm & (S_LEN-1), hh = gc >> 6, dd = gc & 63;
          dst16[(((long)(bb*NH + hh))*S_LEN + ss)*DH + dd] = f2b(val);
        }
  }
}

// ---------------- original GEMM body (bf16 both sides) for out-proj --------
__device__ __forceinline__ void gemm_body(const u16* __restrict__ X, const u16* __restrict__ WT,
    const float* __restrict__ bias, float* __restrict__ dst32,
    int m0, int n0, u16* At, u16* Bt)
{
  const int t = threadIdx.x, lane = t & 63, w = t >> 6;
  const int wr = (w >> 1) * 64, wc = (w & 1) * 64;
  const int li = lane & 15, lg = lane >> 4;
  const f32x4 zero = {0.f, 0.f, 0.f, 0.f};
  f32x4 acc[4][4];
  #pragma unroll
  for (int m = 0; m < 4; ++m)
    #pragma unroll
    for (int n = 0; n < 4; ++n) acc[m][n] = zero;

  for (int kt = 0; kt < DM/64; ++kt){
    stage_tile<128,256>(X  + (long)m0*DM + kt*64, DM, At);
    stage_tile<128,256>(WT + (long)n0*DM + kt*64, DM, Bt);
    __syncthreads();
    #pragma unroll
    for (int ks = 0; ks < 2; ++ks){
      int ch = ks*4 + lg;
      short8 a[4], b[4];
      #pragma unroll
      for (int m = 0; m < 4; ++m) a[m] = frag_ld(At, wr + m*16 + li, ch);
      #pragma unroll
      for (int n = 0; n < 4; ++n) b[n] = frag_ld(Bt, wc + n*16 + li, ch);
      #pragma unroll
      for (int m = 0; m < 4; ++m)
        #pragma unroll
        for (int n = 0; n < 4; ++n) acc[m][n] = mfma16(a[m], b[n], acc[m][n]);
    }
    __syncthreads();
  }

  float bv4[4];
  #pragma unroll
  for (int n = 0; n < 4; ++n) bv4[n] = bias[n0 + wc + n*16 + li];
  #pragma unroll
  for (int m = 0; m < 4; ++m)
    #pragma unroll
    for (int n = 0; n < 4; ++n)
      #pragma unroll
      for (int r = 0; r < 4; ++r){
        int gm = m0 + wr + m*16 + lg*4 + r;
        int gc = n0 + wc + n*16 + li;
        dst32[(long)gm*DM + gc] = acc[m][n][r] + bv4[n];
      }
}

// QKV GEMM with fused f32->bf16 cast of the activation side.
__global__ __launch_bounds__(256) void k_gemm_qkv(
    const float* __restrict__ qf, const float* __restrict__ kf, const float* __restrict__ vf,
    const u16* __restrict__ wtq, const u16* __restrict__ wtk, const u16* __restrict__ wtv,
    const float* __restrict__ bq, const float* __restrict__ bk, const float* __restrict__ bv,
    u16* __restrict__ Qw, u16* __restrict__ Kw, u16* __restrict__ VTw)
{
  __shared__ u16 At[128*64], Bt[128*64];
  int bid = blockIdx.x;
  int xcd = bid & 7, j = bid >> 3;           // j in [0,96)
  int z = j >> 5, tt = j & 31;
  int mi = xcd*4 + (tt >> 3), n = tt & 7;    // mi in [0,32), n in [0,8)
  if (z == 2){
    // swapped: A = wtv (bf16, dm rows), B = v input (f32, b*s rows) -> VT
    gemm_body_fused(wtv, vf, 0, bv, VTw, 1, n*128, mi*128, At, Bt);
  } else {
    const float* X = (z==0)?qf:kf;
    const u16* WT  = (z==0)?wtq:wtk;
    const float* B = (z==0)?bq:bk;
    u16* dst = (z==0)?Qw:Kw;
    gemm_body_fused(X, WT, 1, B, dst, 0, mi*128, n*128, At, Bt);
  }
}

__global__ __launch_bounds__(256) void k_gemm_out(
    const u16* __restrict__ ctx, const u16* __restrict__ wto,
    const float* __restrict__ bo, float* __restrict__ out)
{
  __shared__ u16 At[128*64], Bt[128*64];
  int bid = blockIdx.x;
  int xcd = bid & 7, tt = bid >> 3;          // tt in [0,32)
  int mi = xcd*4 + (tt >> 3), n = tt & 7;
  gemm_body(ctx, wto, bo, out, mi*128, n*128, At, Bt);
}

// ---- attention sweep 1: denominators, k-split 2-way, 128 q-rows/block -----
// Swapped QK^T: mfma32(A=K, B=Q); max-free softmax via raw exp2; lsum in-lane.
__global__ __launch_bounds__(256) void k_attn1(const u16* __restrict__ Q,
    const u16* __restrict__ K, const float* __restrict__ maskb,
    float* __restrict__ lp0, float* __restrict__ lp1)
{
  __shared__ u16 Kt[2][64*64];
  const int t = threadIdx.x, lane = t & 63, w = t >> 6;   // w in {0..3}
  const int lq = lane & 31, hi = lane >> 5;
  const int bid = blockIdx.x;
  const int xcd = bid & 7, j = bid >> 3;     // j in [0,128)
  const int kh = j & 1, jj = j >> 1;         // jj in [0,64)
  const int bh = xcd + 8*(jj & 3);           // 4 heads per XCD
  const int q0 = (jj >> 2) * 128;            // 16 q-tiles of 128 per head
  const int b = bh >> 4;
  const int k0 = kh * (S_LEN/2);             // this block's k-range base
  const u16* Qb = Q + ((long)bh*S_LEN + q0 + w*32 + lq)*DH;
  short8 qa[4];
  #pragma unroll
  for (int ds = 0; ds < 4; ++ds) qa[ds] = *(const short8*)(Qb + ds*16 + hi*8);
  const float* mb_g = maskb + b*S_LEN + k0;
  const u16* Kb = K + ((long)bh*S_LEN + k0)*DH;

  float lsum = 0.f;
  stage_tile<64,256>(Kb, DH, Kt[0]);
  __syncthreads();
  for (int tt = 0; tt < S_LEN/128; ++tt){    // 16 iters of 64 k-rows
    const u16* cur = Kt[tt & 1];
    if (tt + 1 < S_LEN/128)
      stage_tile<64,256>(Kb + (long)(tt+1)*64*DH, DH, Kt[(tt+1) & 1]);
    #pragma unroll
    for (int kt = 0; kt < 2; ++kt){
      f32x16 acc = {};
      __builtin_amdgcn_s_setprio(1);
      #pragma unroll
      for (int ds = 0; ds < 4; ++ds)
        acc = mfma32(frag_ld(cur, kt*32 + lq, ds*2 + hi), qa[ds], acc);
      __builtin_amdgcn_s_setprio(0);
      #pragma unroll
      for (int rg = 0; rg < 4; ++rg){
        f32x4 mb = *(const f32x4*)(mb_g + tt*64 + kt*32 + rg*8 + hi*4);
        #pragma unroll
        for (int jj2 = 0; jj2 < 4; ++jj2)
          lsum += EXP2(acc[rg*4+jj2]*SC2 + mb[jj2]);
      }
    }
    __syncthreads();
  }
  lsum += __shfl_xor(lsum, 32);
  if (hi == 0){
    float* lp = kh ? lp1 : lp0;
    lp[bh*S_LEN + q0 + w*32 + lq] = lsum;
  }
}

// ---- attention sweep 2: p -> Pt, PV FIRST, then readback attn store -------
// Round-21 reorder: PV's MFMA cluster issues immediately after the Pt pack;
// the readback's LDS reads + 8 f32x4 global stores then fill the MFMA
// shadow (separate pipes) instead of preceding it serially.
__global__ __launch_bounds__(256) void k_attn2(const u16* __restrict__ Q,
    const u16* __restrict__ K, const u16* __restrict__ VT,
    const float* __restrict__ maskb, const float* __restrict__ lp0,
    const float* __restrict__ lp1, float* __restrict__ attn, u16* __restrict__ ctx)
{
  __shared__ u16 Kt[2][64*64], Vt[2][64*64], Pt[128*64];
  const int t = threadIdx.x, lane = t & 63, w = t >> 6;
  const int lq = lane & 31, hi = lane >> 5;
  const int bid = blockIdx.x;
  const int xcd = bid & 7, j = bid >> 3;     // j in [0,64)
  const int bh = xcd + 8*(j & 3);            // 4 heads per XCD
  const int q0 = (j >> 2) * 128;             // 16 q-tiles of 128
  const int b = bh >> 4;
  const u16* Qb = Q + ((long)bh*S_LEN + q0 + w*32 + lq)*DH;
  short8 qa[4];
  #pragma unroll
  for (int ds = 0; ds < 4; ++ds) qa[ds] = *(const short8*)(Qb + ds*16 + hi*8);
  const float* mb_g = maskb + b*S_LEN;
  const long lbase = (long)bh*S_LEN + q0 + w*32;

  // readback normalizers: rows i*4 + (lane>>4) within wave's 32
  float rlw[8];
  #pragma unroll
  for (int i = 0; i < 8; ++i){
    int qq = i*4 + (lane >> 4);
    rlw[i] = 1.f / (lp0[lbase + qq] + lp1[lbase + qq]);
  }

  f32x16 cacc[2] = {};
  const int prow = w*32 + lq;
  const int pswz = (prow & 7) << 4;

  stage_tile<64,256>(K  + (long)bh*S_LEN*DH, DH, Kt[0]);
  stage_tile<64,256>(VT + (long)bh*DH*S_LEN, S_LEN, Vt[0]);
  __syncthreads();
  for (int tt = 0; tt < S_LEN/64; ++tt){
    const int cur = tt & 1;
    if (tt + 1 < S_LEN/64){
      stage_tile<64,256>(K  + ((long)bh*S_LEN + (tt+1)*64)*DH, DH, Kt[cur^1]);
      stage_tile<64,256>(VT + (long)bh*DH*S_LEN + (tt+1)*64, S_LEN, Vt[cur^1]);
    }
    #pragma unroll
    for (int kt = 0; kt < 2; ++kt){
      f32x16 acc = {};
      __builtin_amdgcn_s_setprio(1);
      #pragma unroll
      for (int ds = 0; ds < 4; ++ds)
        acc = mfma32(frag_ld(Kt[cur], kt*32 + lq, ds*2 + hi), qa[ds], acc);
      __builtin_amdgcn_s_setprio(0);
      #pragma unroll
      for (int rg = 0; rg < 4; ++rg){
        f32x4 mb = *(const f32x4*)(mb_g + tt*64 + kt*32 + rg*8 + hi*4);
        float p0 = EXP2(acc[rg*4+0]*SC2 + mb[0]);
        float p1 = EXP2(acc[rg*4+1]*SC2 + mb[1]);
        float p2 = EXP2(acc[rg*4+2]*SC2 + mb[2]);
        float p3 = EXP2(acc[rg*4+3]*SC2 + mb[3]);
        uint2 pu;
        pu.x = cvtpk(p0, p1);
        pu.y = cvtpk(p2, p3);
        int off = (prow*128 + (kt*32 + rg*8 + hi*4)*2) ^ pswz;
        *(uint2*)((char*)Pt + off) = pu;
      }
    }
    // PV FIRST: A = P[q][k] (wave-private rows), B = VT[d][k]
    short8 pa[4];
    #pragma unroll
    for (int ks = 0; ks < 4; ++ks) pa[ks] = frag_ld(Pt, prow, ks*2 + hi);
    __builtin_amdgcn_s_setprio(1);
    #pragma unroll
    for (int dh = 0; dh < 2; ++dh)
      #pragma unroll
      for (int ks = 0; ks < 4; ++ks)
        cacc[dh] = mfma32(pa[ks], frag_ld(Vt[cur], dh*32 + lq, ks*2 + hi), cacc[dh]);
    __builtin_amdgcn_s_setprio(0);
    // coalesced attn write in the PV-MFMA shadow: wave reads back its own
    // 32 Pt rows row-major (same-wave LDS write->read, no barrier needed)
    #pragma unroll
    for (int i = 0; i < 8; ++i){
      int rr = i*4 + (lane >> 4);
      int ch8 = lane & 15;
      int roff = ((w*32 + rr)*128 + ch8*8) ^ ((rr & 7) << 4);
      uint2 pr = *(const uint2*)((const char*)Pt + roff);
      f32x4 av;
      av[0] = b2f((u16)(pr.x & 0xffffu)) * rlw[i];
      av[1] = b2f((u16)(pr.x >> 16))     * rlw[i];
      av[2] = b2f((u16)(pr.y & 0xffffu)) * rlw[i];
      av[3] = b2f((u16)(pr.y >> 16))     * rlw[i];
      *(f32x4*)(attn + ((long)bh*S_LEN + q0 + w*32 + rr)*S_LEN + tt*64 + ch8*4) = av;
    }
    // counted-vmcnt barrier: stage+mask loads (issued first) must be done;
    // the 8 attn stores (issued last) keep floating across the barrier.
    asm volatile("s_waitcnt vmcnt(8)" ::: "memory");
    __builtin_amdgcn_sched_barrier(0);
    __builtin_amdgcn_s_barrier();
  }

  // epilogue: D rows q = crow(r), cols d = dh*32 + lq
  int bb = bh >> 4, hh = bh & 15;
  #pragma unroll
  for (int r = 0; r < 16; ++r){
    int qrow = (r & 3) + 8*(r >> 2) + 4*hi;
    float rle = 1.f / (lp0[lbase + qrow] + lp1[lbase + qrow]);
    #pragma unroll
    for (int dh = 0; dh < 2; ++dh){
      float val = cacc[dh][r] * rle;
      ctx[((long)bb*S_LEN + q0 + w*32 + qrow)*DM + hh*DH + dh*32 + lq] = f2b(val);
    }
  }
}

extern "C" void kernel_launch(void* const* d_in, const int* in_sizes, int n_in,
                              void* d_out, int out_size, void* d_ws, size_t ws_size,
                              hipStream_t stream)
{
  const float* v_in = (const float*)d_in[0];
  const float* k_in = (const float*)d_in[1];
  const float* q_in = (const float*)d_in[2];
  const float* mask = (const float*)d_in[3];
  const float* wq = (const float*)d_in[4];
  const float* wk = (const float*)d_in[5];
  const float* wv = (const float*)d_in[6];
  const float* wo = (const float*)d_in[7];
  const float* bq = (const float*)d_in[8];
  const float* bk = (const float*)d_in[9];
  const float* bv = (const float*)d_in[10];
  const float* bo = (const float*)d_in[11];

  float* out  = (float*)d_out;
  float* attn = out + (long)2*S_LEN*DM;      // out: 4,194,304 f32, then attn

  char* ws = (char*)d_ws;
  const long MW = 1024*1024;
  u16*  wtq = (u16*)(ws);                    // 2 MB each
  u16*  wtk = (u16*)(ws + 2*MW);
  u16*  wtv = (u16*)(ws + 4*MW);
  u16*  wto = (u16*)(ws + 6*MW);
  u16*  Qw  = (u16*)(ws + 35*MW);            // [32][2048][64] bf16
  u16*  Kw  = (u16*)(ws + 44*MW);            // [32][2048][64]
  u16*  VTw = (u16*)(ws + 53*MW);            // [32][64][2048]
  u16*  ctx = (u16*)(ws + 8*MW);             // [4096][1024] bf16
  float* lp0   = (float*)(ws + 62*MW);       // 256 KB partial denominators
  float* lp1   = (float*)(ws + 62*MW + 262144);
  float* maskb = (float*)(ws + 63*MW);       // 16 KB

  k_pre<<<1040, 256, 0, stream>>>(wq, wk, wv, wo, wtq, wtk, wtv, wto, mask, maskb);
  k_gemm_qkv<<<768, 256, 0, stream>>>(q_in, k_in, v_in, wtq, wtk, wtv,
                                      bq, bk, bv, Qw, Kw, VTw);
  k_attn1<<<1024, 256, 0, stream>>>(Qw, Kw, maskb, lp0, lp1);
  k_attn2<<<512, 256, 0, stream>>>(Qw, Kw, VTw, maskb, lp0, lp1, attn, ctx);
  k_gemm_out<<<256, 256, 0, stream>>>(ctx, wto, bo, out);
}

// Round 22
// 286.149 us; speedup vs baseline: 1.0197x; 1.0197x over previous
//
#include <hip/hip_runtime.h>

#define S_LEN 2048
#define DM 1024
#define NH 16
#define DH 64

typedef __attribute__((ext_vector_type(8))) short short8;
typedef __attribute__((ext_vector_type(4))) float f32x4;
typedef __attribute__((ext_vector_type(16))) float f32x16;
typedef unsigned short u16;
typedef unsigned int u32;

__device__ __forceinline__ u16 f2b(float f){
  union { float f; u32 u; } v; v.f = f;
  return (u16)((v.u + 0x7fffu + ((v.u >> 16) & 1u)) >> 16);
}
__device__ __forceinline__ float b2f(u16 h){
  union { u32 u; float f; } v; v.u = ((u32)h) << 16; return v.f;
}
// packed f32x2 -> bf16x2 (RTNE), single HW instruction
__device__ __forceinline__ u32 cvtpk(float lo, float hi){
  u32 r;
  asm("v_cvt_pk_bf16_f32 %0, %1, %2" : "=v"(r) : "v"(lo), "v"(hi));
  return r;
}

__device__ __forceinline__ f32x4 mfma16(short8 a, short8 b, f32x4 c){
  return __builtin_amdgcn_mfma_f32_16x16x32_bf16(a, b, c, 0, 0, 0);
}
__device__ __forceinline__ f32x16 mfma32(short8 a, short8 b, f32x16 c){
  return __builtin_amdgcn_mfma_f32_32x32x16_bf16(a, b, c, 0, 0, 0);
}

#define SC2 0.18033688f   /* 0.125 * log2(e) */

// raw v_exp_f32 (2^x). exp2f() without fast-math goes through OCML with
// denormal fixup (~6 extra VALU/exp = +20us measured in round 14).
#if defined(__has_builtin)
#  if __has_builtin(__builtin_amdgcn_exp2f)
#    define EXP2(x) __builtin_amdgcn_exp2f(x)
#  else
#    define EXP2(x) __expf((x) * 0.6931472f)
#  endif
#else
#  define EXP2(x) __expf((x) * 0.6931472f)
#endif

// Stage an R x 64-bf16 tile (128B rows) into LDS via global_load_lds (16B),
// XOR-swizzled: LDS stays linear, the SOURCE column-chunk is pre-swizzled
// (chunk ^= row&7), and reads apply the same XOR (both-sides rule).
// NT = threads in block.
template<int R, int NT>
__device__ __forceinline__ void stage_tile(const u16* src, int ld, u16* lds){
  const int t = threadIdx.x;
  #pragma unroll
  for (int it = 0; it < R*8/NT; ++it){
    int idx = it*NT + t;
    int row = idx >> 3;                       // 8 x 16B chunks per row
    int ch  = (idx & 7) ^ (row & 7);
    const u16* g = src + row*ld + ch*8;
    u16* l = lds + (it*NT + (t & ~63))*8;     // wave-uniform LDS base
    __builtin_amdgcn_global_load_lds((const __attribute__((address_space(1))) void*)g,
                                     (__attribute__((address_space(3))) void*)l, 16, 0, 0);
  }
}

// Reg-stage an R x 64-bf16 tile FROM AN F32 SOURCE (fused cast): coalesced
// f32x4 loads -> cvt_pk -> ds_write_b128 at the same linear-swizzled offsets
// the gload_lds path produces, so frag_ld is unchanged.
template<int R, int NT>
__device__ __forceinline__ void stage_tile_f32(const float* src, int ld, u16* lds){
  const int t = threadIdx.x;
  #pragma unroll
  for (int it = 0; it < R*8/NT; ++it){
    int idx = it*NT + t;
    int row = idx >> 3;
    int ch  = (idx & 7) ^ (row & 7);
    const float* g = src + (long)row*ld + ch*8;
    f32x4 a = *(const f32x4*)g;
    f32x4 b = *(const f32x4*)(g + 4);
    union { u32 u[4]; short8 s; } o;
    o.u[0] = cvtpk(a[0], a[1]); o.u[1] = cvtpk(a[2], a[3]);
    o.u[2] = cvtpk(b[0], b[1]); o.u[3] = cvtpk(b[2], b[3]);
    *(short8*)(lds + (long)idx*8) = o.s;
  }
}

// read one MFMA fragment (8 contiguous bf16 of row `row`, chunk `ch`)
__device__ __forceinline__ short8 frag_ld(const u16* tile, int row, int ch){
  int off = (row*128 + ch*16) ^ ((row & 7) << 4);
  return *(const short8*)((const char*)tile + off);
}

// ------ fused preprocessing: transpose+cast weights, maskb -----------------
__global__ __launch_bounds__(256) void k_pre(
    const float* __restrict__ wq, const float* __restrict__ wk,
    const float* __restrict__ wv, const float* __restrict__ wo,
    u16* __restrict__ oq, u16* __restrict__ ok, u16* __restrict__ ov, u16* __restrict__ oo,
    const float* __restrict__ mask, float* __restrict__ maskb)
{
  __shared__ float tl[64][65];
  const int bid = blockIdx.x, t = threadIdx.x;
  if (bid < 1024){
    int z = bid >> 8, rem = bid & 255;
    const float* W = (z==0)?wq:(z==1)?wk:(z==2)?wv:wo;
    u16* O = (z==0)?oq:(z==1)?ok:(z==2)?ov:oo;
    int k0 = (rem >> 4)*64, n0 = (rem & 15)*64;
    #pragma unroll
    for (int i = 0; i < 16; ++i){
      int idx2 = i*256 + t;
      int row = idx2 >> 6, col = idx2 & 63;
      tl[row][col] = W[(long)(k0+row)*DM + n0 + col];
    }
    __syncthreads();
    #pragma unroll
    for (int i = 0; i < 16; ++i){
      int idx2 = i*256 + t;
      int n = idx2 >> 6, kk = idx2 & 63;
      O[(long)(n0+n)*DM + k0 + kk] = f2b(tl[kk][n]);
    }
  } else {
    int i = (bid - 1024)*256 + t;            // 4096 elements
    maskb[i] = -1.44269504e9f * mask[i];
  }
}

// -------- fused QKV GEMM body: one side staged from f32 (cast fused) -------
__device__ __forceinline__ void gemm_body_fused(
    const void* __restrict__ Asrc, const void* __restrict__ Bsrc, int af32,
    const float* __restrict__ bias, u16* __restrict__ dst16,
    int layout, int m0, int n0, u16* At, u16* Bt)
{
  const int t = threadIdx.x, lane = t & 63, w = t >> 6;
  const int wr = (w >> 1) * 64, wc = (w & 1) * 64;
  const int li = lane & 15, lg = lane >> 4;
  const f32x4 zero = {0.f, 0.f, 0.f, 0.f};
  f32x4 acc[4][4];
  #pragma unroll
  for (int m = 0; m < 4; ++m)
    #pragma unroll
    for (int n = 0; n < 4; ++n) acc[m][n] = zero;

  for (int kt = 0; kt < DM/64; ++kt){
    if (af32){
      stage_tile_f32<128,256>((const float*)Asrc + (long)m0*DM + kt*64, DM, At);
      stage_tile<128,256>((const u16*)Bsrc + (long)n0*DM + kt*64, DM, Bt);
    } else {
      stage_tile<128,256>((const u16*)Asrc + (long)m0*DM + kt*64, DM, At);
      stage_tile_f32<128,256>((const float*)Bsrc + (long)n0*DM + kt*64, DM, Bt);
    }
    __syncthreads();
    #pragma unroll
    for (int ks = 0; ks < 2; ++ks){
      int ch = ks*4 + lg;
      short8 a[4], b[4];
      #pragma unroll
      for (int m = 0; m < 4; ++m) a[m] = frag_ld(At, wr + m*16 + li, ch);
      #pragma unroll
      for (int n = 0; n < 4; ++n) b[n] = frag_ld(Bt, wc + n*16 + li, ch);
      #pragma unroll
      for (int m = 0; m < 4; ++m)
        #pragma unroll
        for (int n = 0; n < 4; ++n) acc[m][n] = mfma16(a[m], b[n], acc[m][n]);
    }
    __syncthreads();
  }

  if (layout == 1){
    f32x4 bm[4];
    #pragma unroll
    for (int m = 0; m < 4; ++m) bm[m] = *(const f32x4*)(bias + m0 + wr + m*16 + lg*4);
    #pragma unroll
    for (int m = 0; m < 4; ++m)
      #pragma unroll
      for (int n = 0; n < 4; ++n)
        #pragma unroll
        for (int r = 0; r < 4; ++r){
          int gm = m0 + wr + m*16 + lg*4 + r;    // dm index -> (h,d)
          int gc = n0 + wc + n*16 + li;          // b*s index
          int hh = gm >> 6, dd = gm & 63, bb = gc >> 11, ss = gc & (S_LEN-1);
          dst16[(((long)(bb*NH + hh))*DH + dd)*S_LEN + ss] = f2b(acc[m][n][r] + bm[m][r]);
        }
  } else {
    float bv4[4];
    #pragma unroll
    for (int n = 0; n < 4; ++n) bv4[n] = bias[n0 + wc + n*16 + li];
    #pragma unroll
    for (int m = 0; m < 4; ++m)
      #pragma unroll
      for (int n = 0; n < 4; ++n)
        #pragma unroll
        for (int r = 0; r < 4; ++r){
          int gm = m0 + wr + m*16 + lg*4 + r;
          int gc = n0 + wc + n*16 + li;
          float val = acc[m][n][r] + bv4[n];
          int bb = gm >> 11, ss = gm & (S_LEN-1), hh = gc >> 6, dd = gc & 63;
          dst16[(((long)(bb*NH + hh))*S_LEN + ss)*DH + dd] = f2b(val);
        }
  }
}

// ---------------- original GEMM body (bf16 both sides) for out-proj --------
__device__ __forceinline__ void gemm_body(const u16* __restrict__ X, const u16* __restrict__ WT,
    const float* __restrict__ bias, float* __restrict__ dst32,
    int m0, int n0, u16* At, u16* Bt)
{
  const int t = threadIdx.x, lane = t & 63, w = t >> 6;
  const int wr = (w >> 1) * 64, wc = (w & 1) * 64;
  const int li = lane & 15, lg = lane >> 4;
  const f32x4 zero = {0.f, 0.f, 0.f, 0.f};
  f32x4 acc[4][4];
  #pragma unroll
  for (int m = 0; m < 4; ++m)
    #pragma unroll
    for (int n = 0; n < 4; ++n) acc[m][n] = zero;

  for (int kt = 0; kt < DM/64; ++kt){
    stage_tile<128,256>(X  + (long)m0*DM + kt*64, DM, At);
    stage_tile<128,256>(WT + (long)n0*DM + kt*64, DM, Bt);
    __syncthreads();
    #pragma unroll
    for (int ks = 0; ks < 2; ++ks){
      int ch = ks*4 + lg;
      short8 a[4], b[4];
      #pragma unroll
      for (int m = 0; m < 4; ++m) a[m] = frag_ld(At, wr + m*16 + li, ch);
      #pragma unroll
      for (int n = 0; n < 4; ++n) b[n] = frag_ld(Bt, wc + n*16 + li, ch);
      #pragma unroll
      for (int m = 0; m < 4; ++m)
        #pragma unroll
        for (int n = 0; n < 4; ++n) acc[m][n] = mfma16(a[m], b[n], acc[m][n]);
    }
    __syncthreads();
  }

  float bv4[4];
  #pragma unroll
  for (int n = 0; n < 4; ++n) bv4[n] = bias[n0 + wc + n*16 + li];
  #pragma unroll
  for (int m = 0; m < 4; ++m)
    #pragma unroll
    for (int n = 0; n < 4; ++n)
      #pragma unroll
      for (int r = 0; r < 4; ++r){
        int gm = m0 + wr + m*16 + lg*4 + r;
        int gc = n0 + wc + n*16 + li;
        dst32[(long)gm*DM + gc] = acc[m][n][r] + bv4[n];
      }
}

// QKV GEMM with fused f32->bf16 cast of the activation side.
__global__ __launch_bounds__(256) void k_gemm_qkv(
    const float* __restrict__ qf, const float* __restrict__ kf, const float* __restrict__ vf,
    const u16* __restrict__ wtq, const u16* __restrict__ wtk, const u16* __restrict__ wtv,
    const float* __restrict__ bq, const float* __restrict__ bk, const float* __restrict__ bv,
    u16* __restrict__ Qw, u16* __restrict__ Kw, u16* __restrict__ VTw)
{
  __shared__ u16 At[128*64], Bt[128*64];
  int bid = blockIdx.x;
  int xcd = bid & 7, j = bid >> 3;           // j in [0,96)
  int z = j >> 5, tt = j & 31;
  int mi = xcd*4 + (tt >> 3), n = tt & 7;    // mi in [0,32), n in [0,8)
  if (z == 2){
    // swapped: A = wtv (bf16, dm rows), B = v input (f32, b*s rows) -> VT
    gemm_body_fused(wtv, vf, 0, bv, VTw, 1, n*128, mi*128, At, Bt);
  } else {
    const float* X = (z==0)?qf:kf;
    const u16* WT  = (z==0)?wtq:wtk;
    const float* B = (z==0)?bq:bk;
    u16* dst = (z==0)?Qw:Kw;
    gemm_body_fused(X, WT, 1, B, dst, 0, mi*128, n*128, At, Bt);
  }
}

__global__ __launch_bounds__(256) void k_gemm_out(
    const u16* __restrict__ ctx, const u16* __restrict__ wto,
    const float* __restrict__ bo, float* __restrict__ out)
{
  __shared__ u16 At[128*64], Bt[128*64];
  int bid = blockIdx.x;
  int xcd = bid & 7, tt = bid >> 3;          // tt in [0,32)
  int mi = xcd*4 + (tt >> 3), n = tt & 7;
  gemm_body(ctx, wto, bo, out, mi*128, n*128, At, Bt);
}

// ---- attention sweep 1: denominators, k-split 2-way, 128 q-rows/block -----
// Swapped QK^T: mfma32(A=K, B=Q); max-free softmax via raw exp2; lsum in-lane.
__global__ __launch_bounds__(256) void k_attn1(const u16* __restrict__ Q,
    const u16* __restrict__ K, const float* __restrict__ maskb,
    float* __restrict__ lp0, float* __restrict__ lp1)
{
  __shared__ u16 Kt[2][64*64];
  const int t = threadIdx.x, lane = t & 63, w = t >> 6;   // w in {0..3}
  const int lq = lane & 31, hi = lane >> 5;
  const int bid = blockIdx.x;
  const int xcd = bid & 7, j = bid >> 3;     // j in [0,128)
  const int kh = j & 1, jj = j >> 1;         // jj in [0,64)
  const int bh = xcd + 8*(jj & 3);           // 4 heads per XCD
  const int q0 = (jj >> 2) * 128;            // 16 q-tiles of 128 per head
  const int b = bh >> 4;
  const int k0 = kh * (S_LEN/2);             // this block's k-range base
  const u16* Qb = Q + ((long)bh*S_LEN + q0 + w*32 + lq)*DH;
  short8 qa[4];
  #pragma unroll
  for (int ds = 0; ds < 4; ++ds) qa[ds] = *(const short8*)(Qb + ds*16 + hi*8);
  const float* mb_g = maskb + b*S_LEN + k0;
  const u16* Kb = K + ((long)bh*S_LEN + k0)*DH;

  float lsum = 0.f;
  stage_tile<64,256>(Kb, DH, Kt[0]);
  __syncthreads();
  for (int tt = 0; tt < S_LEN/128; ++tt){    // 16 iters of 64 k-rows
    const u16* cur = Kt[tt & 1];
    if (tt + 1 < S_LEN/128)
      stage_tile<64,256>(Kb + (long)(tt+1)*64*DH, DH, Kt[(tt+1) & 1]);
    #pragma unroll
    for (int kt = 0; kt < 2; ++kt){
      f32x16 acc = {};
      __builtin_amdgcn_s_setprio(1);
      #pragma unroll
      for (int ds = 0; ds < 4; ++ds)
        acc = mfma32(frag_ld(cur, kt*32 + lq, ds*2 + hi), qa[ds], acc);
      __builtin_amdgcn_s_setprio(0);
      #pragma unroll
      for (int rg = 0; rg < 4; ++rg){
        f32x4 mb = *(const f32x4*)(mb_g + tt*64 + kt*32 + rg*8 + hi*4);
        #pragma unroll
        for (int jj2 = 0; jj2 < 4; ++jj2)
          lsum += EXP2(acc[rg*4+jj2]*SC2 + mb[jj2]);
      }
    }
    __syncthreads();
  }
  lsum += __shfl_xor(lsum, 32);
  if (hi == 0){
    float* lp = kh ? lp1 : lp0;
    lp[bh*S_LEN + q0 + w*32 + lq] = lsum;
  }
}

// ---- attention sweep 2: p -> Pt(bf16), coalesced readback attn store, PV --
// Pt readback IS the store-formatting stage: 16 lanes x 16B = 256B
// contiguous segments (round-13's direct-store 32x32B scatter cost +47us).
// Counted-vmcnt barrier already defers the stores into the next iteration's
// QK phase (round-21's explicit reorder was null/negative).
__global__ __launch_bounds__(256) void k_attn2(const u16* __restrict__ Q,
    const u16* __restrict__ K, const u16* __restrict__ VT,
    const float* __restrict__ maskb, const float* __restrict__ lp0,
    const float* __restrict__ lp1, float* __restrict__ attn, u16* __restrict__ ctx)
{
  __shared__ u16 Kt[2][64*64], Vt[2][64*64], Pt[128*64];
  const int t = threadIdx.x, lane = t & 63, w = t >> 6;
  const int lq = lane & 31, hi = lane >> 5;
  const int bid = blockIdx.x;
  const int xcd = bid & 7, j = bid >> 3;     // j in [0,64)
  const int bh = xcd + 8*(j & 3);            // 4 heads per XCD
  const int q0 = (j >> 2) * 128;             // 16 q-tiles of 128
  const int b = bh >> 4;
  const u16* Qb = Q + ((long)bh*S_LEN + q0 + w*32 + lq)*DH;
  short8 qa[4];
  #pragma unroll
  for (int ds = 0; ds < 4; ++ds) qa[ds] = *(const short8*)(Qb + ds*16 + hi*8);
  const float* mb_g = maskb + b*S_LEN;
  const long lbase = (long)bh*S_LEN + q0 + w*32;

  // readback normalizers: rows i*4 + (lane>>4) within wave's 32
  float rlw[8];
  #pragma unroll
  for (int i = 0; i < 8; ++i){
    int qq = i*4 + (lane >> 4);
    rlw[i] = 1.f / (lp0[lbase + qq] + lp1[lbase + qq]);
  }

  f32x16 cacc[2] = {};
  const int prow = w*32 + lq;
  const int pswz = (prow & 7) << 4;

  stage_tile<64,256>(K  + (long)bh*S_LEN*DH, DH, Kt[0]);
  stage_tile<64,256>(VT + (long)bh*DH*S_LEN, S_LEN, Vt[0]);
  __syncthreads();
  for (int tt = 0; tt < S_LEN/64; ++tt){
    const int cur = tt & 1;
    if (tt + 1 < S_LEN/64){
      stage_tile<64,256>(K  + ((long)bh*S_LEN + (tt+1)*64)*DH, DH, Kt[cur^1]);
      stage_tile<64,256>(VT + (long)bh*DH*S_LEN + (tt+1)*64, S_LEN, Vt[cur^1]);
    }
    #pragma unroll
    for (int kt = 0; kt < 2; ++kt){
      f32x16 acc = {};
      __builtin_amdgcn_s_setprio(1);
      #pragma unroll
      for (int ds = 0; ds < 4; ++ds)
        acc = mfma32(frag_ld(Kt[cur], kt*32 + lq, ds*2 + hi), qa[ds], acc);
      __builtin_amdgcn_s_setprio(0);
      #pragma unroll
      for (int rg = 0; rg < 4; ++rg){
        f32x4 mb = *(const f32x4*)(mb_g + tt*64 + kt*32 + rg*8 + hi*4);
        float p0 = EXP2(acc[rg*4+0]*SC2 + mb[0]);
        float p1 = EXP2(acc[rg*4+1]*SC2 + mb[1]);
        float p2 = EXP2(acc[rg*4+2]*SC2 + mb[2]);
        float p3 = EXP2(acc[rg*4+3]*SC2 + mb[3]);
        uint2 pu;
        pu.x = (u32)f2b(p0) | ((u32)f2b(p1) << 16);
        pu.y = (u32)f2b(p2) | ((u32)f2b(p3) << 16);
        int off = (prow*128 + (kt*32 + rg*8 + hi*4)*2) ^ pswz;
        *(uint2*)((char*)Pt + off) = pu;
      }
    }
    // coalesced attn write: wave reads back its own 32 Pt rows row-major
    // (same-wave LDS write->read: compiler-tracked lgkmcnt, no barrier)
    #pragma unroll
    for (int i = 0; i < 8; ++i){
      int rr = i*4 + (lane >> 4);
      int ch8 = lane & 15;
      int roff = ((w*32 + rr)*128 + ch8*8) ^ ((rr & 7) << 4);
      uint2 pr = *(const uint2*)((const char*)Pt + roff);
      f32x4 av;
      av[0] = b2f((u16)(pr.x & 0xffffu)) * rlw[i];
      av[1] = b2f((u16)(pr.x >> 16))     * rlw[i];
      av[2] = b2f((u16)(pr.y & 0xffffu)) * rlw[i];
      av[3] = b2f((u16)(pr.y >> 16))     * rlw[i];
      *(f32x4*)(attn + ((long)bh*S_LEN + q0 + w*32 + rr)*S_LEN + tt*64 + ch8*4) = av;
    }
    // PV: A = P[q][k] (wave-private rows), B = VT[d][k]
    short8 pa[4];
    #pragma unroll
    for (int ks = 0; ks < 4; ++ks) pa[ks] = frag_ld(Pt, prow, ks*2 + hi);
    __builtin_amdgcn_s_setprio(1);
    #pragma unroll
    for (int dh = 0; dh < 2; ++dh)
      #pragma unroll
      for (int ks = 0; ks < 4; ++ks)
        cacc[dh] = mfma32(pa[ks], frag_ld(Vt[cur], dh*32 + lq, ks*2 + hi), cacc[dh]);
    __builtin_amdgcn_s_setprio(0);
    // counted-vmcnt barrier: stage+mask loads (issued first) must be done;
    // the 8 attn stores (issued last) keep floating across the barrier.
    asm volatile("s_waitcnt vmcnt(8)" ::: "memory");
    __builtin_amdgcn_sched_barrier(0);
    __builtin_amdgcn_s_barrier();
  }

  // epilogue: D rows q = crow(r), cols d = dh*32 + lq
  int bb = bh >> 4, hh = bh & 15;
  #pragma unroll
  for (int r = 0; r < 16; ++r){
    int qrow = (r & 3) + 8*(r >> 2) + 4*hi;
    float rle = 1.f / (lp0[lbase + qrow] + lp1[lbase + qrow]);
    #pragma unroll
    for (int dh = 0; dh < 2; ++dh){
      float val = cacc[dh][r] * rle;
      ctx[((long)bb*S_LEN + q0 + w*32 + qrow)*DM + hh*DH + dh*32 + lq] = f2b(val);
    }
  }
}

extern "C" void kernel_launch(void* const* d_in, const int* in_sizes, int n_in,
                              void* d_out, int out_size, void* d_ws, size_t ws_size,
                              hipStream_t stream)
{
  const float* v_in = (const float*)d_in[0];
  const float* k_in = (const float*)d_in[1];
  const float* q_in = (const float*)d_in[2];
  const float* mask = (const float*)d_in[3];
  const float* wq = (const float*)d_in[4];
  const float* wk = (const float*)d_in[5];
  const float* wv = (const float*)d_in[6];
  const float* wo = (const float*)d_in[7];
  const float* bq = (const float*)d_in[8];
  const float* bk = (const float*)d_in[9];
  const float* bv = (const float*)d_in[10];
  const float* bo = (const float*)d_in[11];

  float* out  = (float*)d_out;
  float* attn = out + (long)2*S_LEN*DM;      // out: 4,194,304 f32, then attn

  char* ws = (char*)d_ws;
  const long MW = 1024*1024;
  u16*  wtq = (u16*)(ws);                    // 2 MB each
  u16*  wtk = (u16*)(ws + 2*MW);
  u16*  wtv = (u16*)(ws + 4*MW);
  u16*  wto = (u16*)(ws + 6*MW);
  u16*  Qw  = (u16*)(ws + 35*MW);            // [32][2048][64] bf16
  u16*  Kw  = (u16*)(ws + 44*MW);            // [32][2048][64]
  u16*  VTw = (u16*)(ws + 53*MW);            // [32][64][2048]
  u16*  ctx = (u16*)(ws + 8*MW);             // [4096][1024] bf16
  float* lp0   = (float*)(ws + 62*MW);       // 256 KB partial denominators
  float* lp1   = (float*)(ws + 62*MW + 262144);
  float* maskb = (float*)(ws + 63*MW);       // 16 KB

  k_pre<<<1040, 256, 0, stream>>>(wq, wk, wv, wo, wtq, wtk, wtv, wto, mask, maskb);
  k_gemm_qkv<<<768, 256, 0, stream>>>(q_in, k_in, v_in, wtq, wtk, wtv,
                                      bq, bk, bv, Qw, Kw, VTw);
  k_attn1<<<1024, 256, 0, stream>>>(Qw, Kw, maskb, lp0, lp1);
  k_attn2<<<512, 256, 0, stream>>>(Qw, Kw, VTw, maskb, lp0, lp1, attn, ctx);
  k_gemm_out<<<256, 256, 0, stream>>>(ctx, wto, bo, out);
}